// Round 3
// baseline (547.047 us; speedup 1.0000x reference)
//
#include <hip/hip_runtime.h>
#include <hip/hip_bf16.h>

#define D 128
#define NK 16
#define BT (64*2048)

typedef short bf16x8 __attribute__((ext_vector_type(8)));
typedef float f32x4 __attribute__((ext_vector_type(4)));

__device__ __forceinline__ unsigned short f2bf(float f) {
  unsigned u = __builtin_bit_cast(unsigned, f);
  unsigned r = (u + 0x7FFFu + ((u >> 16) & 1u)) >> 16;   // round-to-nearest-even
  return (unsigned short)r;
}
__device__ __forceinline__ float bf2f(unsigned short h) {
  unsigned u = ((unsigned)h) << 16;
  return __builtin_bit_cast(float, u);
}

// ---------------- Setup: Cholesky -> logdet, Linv (bf16 swizzled image), Lmu = Linv*mu ----------
// 256 threads per state; all hot loops 2D-parallel or register-blocked (no long dependent
// LDS chains — the R2 version's 8128-deep forward-substitution chain was 354 us).
__global__ __launch_bounds__(256) void setup_kernel(const float* __restrict__ sigma,
                                                    const float* __restrict__ mu,
                                                    unsigned short* __restrict__ WG,
                                                    float* __restrict__ LmuG,
                                                    float* __restrict__ ldG,
                                                    float* __restrict__ out) {
  __shared__ float A[D][129];          // sigma -> strictly-lower L (diag kept separately)
  __shared__ float V[D][129];          // Linv (lower), upper zeroed
  __shared__ float T[3][32][33];       // per-pair matmul temps
  __shared__ float diag[D], invd[D], logv[D];
  const int tid = threadIdx.x;
  const int k = blockIdx.x;
  const float* S = sigma + (size_t)k * D * D;

  if (k == 0 && tid == 0) out[0] = 0.f;

  for (int t = tid; t < D * D; t += 256) {
    A[t >> 7][t & 127] = S[t];
    V[t >> 7][t & 127] = 0.f;
  }

  // ---- Cholesky: right-looking rank-1, 2D-parallel trailing update ----
  const int half = tid >> 7, lane = tid & 127;
  for (int j = 0; j < D - 1; ++j) {
    __syncthreads();                    // prior update complete
    const float sq = sqrtf(A[j][j]);    // A[j][j] never overwritten this iter (diag deferred)
    if (tid == 0) diag[j] = sq;
    const float inv = 1.f / sq;
    for (int r = j + 1 + tid; r < D; r += 256) A[r][j] *= inv;
    __syncthreads();                    // column j final
    for (int c = j + 1 + half; c < D; c += 2) {
      const int r = c + lane;
      if (r < D) A[r][c] = fmaf(-A[r][j], A[c][j], A[r][c]);
    }
  }
  __syncthreads();
  if (tid == 0) diag[D - 1] = sqrtf(A[D - 1][D - 1]);
  __syncthreads();
  if (tid < D) {
    const float dg = diag[tid];
    invd[tid] = 1.f / dg;
    logv[tid] = logf(dg);
  }

  // ---- blocked triangular inverse: 4 diag 32x32 blocks, col per thread (chain <= 32) ----
  __syncthreads();
  if (tid < D) {
    const int c = tid, bend = ((c >> 5) + 1) << 5;
    V[c][c] = invd[c];
    for (int r = c + 1; r < bend; ++r) {
      float s = 0.f;
      for (int p = c; p < r; ++p) s += A[r][p] * V[p][c];
      V[r][c] = -s * invd[r];
    }
  }

  // ---- off-diagonal blocks, 3 dependency levels, register-blocked matmuls ----
  // V_ij = -V_ii * (sum_{p-blocks j..i-1} L_ip * V_pj)
  for (int d = 1; d <= 3; ++d) {
    __syncthreads();
    const int npair = 4 - d;
    for (int q = tid; q < npair * 256; q += 256) {       // phase A: M = L*V into T
      const int pair = q >> 8;
      const int r = (q >> 3) & 31;
      const int c4 = (q & 7) << 2;
      const int i0 = (pair + d) << 5, j0 = pair << 5;
      float m0 = 0.f, m1 = 0.f, m2 = 0.f, m3 = 0.f;
      for (int p = 0; p < d * 32; ++p) {
        const float a = A[i0 + r][j0 + p];
        const float* vp = &V[j0 + p][j0 + c4];
        m0 = fmaf(a, vp[0], m0); m1 = fmaf(a, vp[1], m1);
        m2 = fmaf(a, vp[2], m2); m3 = fmaf(a, vp[3], m3);
      }
      T[pair][r][c4] = m0; T[pair][r][c4 + 1] = m1;
      T[pair][r][c4 + 2] = m2; T[pair][r][c4 + 3] = m3;
    }
    __syncthreads();
    for (int q = tid; q < npair * 256; q += 256) {       // phase B: V_ij = -V_ii * M
      const int pair = q >> 8;
      const int r = (q >> 3) & 31;
      const int c4 = (q & 7) << 2;
      const int i0 = (pair + d) << 5, j0 = pair << 5;
      float m0 = 0.f, m1 = 0.f, m2 = 0.f, m3 = 0.f;
      for (int p = 0; p <= r; ++p) {                     // V_ii lower-triangular
        const float a = V[i0 + r][i0 + p];
        const float* tp = &T[pair][p][c4];
        m0 = fmaf(a, tp[0], m0); m1 = fmaf(a, tp[1], m1);
        m2 = fmaf(a, tp[2], m2); m3 = fmaf(a, tp[3], m3);
      }
      V[i0 + r][j0 + c4] = -m0; V[i0 + r][j0 + c4 + 1] = -m1;
      V[i0 + r][j0 + c4 + 2] = -m2; V[i0 + r][j0 + c4 + 3] = -m3;
    }
  }
  __syncthreads();

  // Lmu[k][j] = sum_i Linv[j][i]*mu[k][i]  (V upper = 0 -> uniform loop)
  if (tid < D) {
    const float* muk = mu + k * D;
    float s = 0.f;
    for (int i = 0; i < D; ++i) s = fmaf(V[tid][i], muk[i], s);
    LmuG[k * D + tid] = s;
  }
  if (tid == 0) {
    float s = 0.f;
    for (int i = 0; i < D; ++i) s += logv[i];
    ldG[k] = s;
  }
  // bf16 image of Linv, pre-swizzled so linear global_load_lds lands XOR-swizzled in LDS
  for (int t = tid; t < D * D; t += 256) {
    const int j = t >> 7, i = t & 127;
    WG[(size_t)k * D * D + j * D + (i ^ ((j & 7) << 3))] = f2bf(V[j][i]);
  }
}

__device__ __forceinline__ void stage_tile(const unsigned short* gsrc, unsigned short* lds, int tid) {
#pragma unroll
  for (int c = 0; c < 4; ++c) {
    const int off = c * 4096 + tid * 8;  // u16 units; 16B per lane
    __builtin_amdgcn_global_load_lds(
        (const __attribute__((address_space(1))) unsigned int*)(gsrc + off),
        (__attribute__((address_space(3))) unsigned int*)(lds + off), 16, 0, 0);
  }
}

// ---------------- Main: Z^T = Linv * x^T per state (MFMA), maha = ||Z - Lmu||^2 ----------------
// 512 threads = 8 waves (2 j-groups x 4 bt-groups), 256 points/block, grid = 512
__global__ __launch_bounds__(512, 2) void main_kernel(const float* __restrict__ x,
                                                      const float* __restrict__ probs,
                                                      const unsigned short* __restrict__ WG,
                                                      const float* __restrict__ LmuG,
                                                      const float* __restrict__ ldG,
                                                      float* __restrict__ out) {
  __shared__ unsigned short xbuf[256 * 128];        // 64 KB, XOR-swizzled bf16 x
  __shared__ unsigned short Albuf[2][128 * 128];    // 64 KB, double-buffered swizzled Linv
  __shared__ float Lm[NK * D];                      // 8 KB
  __shared__ unsigned short pT[256 * 17];           // 8.5 KB, bf16 probs (padded stride 17)
  __shared__ float mah2[2][2][256];                 // 8 KB
  __shared__ float ld_s[NK];
  __shared__ float red[256];

  const int tid = threadIdx.x;
  const int ln = tid & 63;
  const int wid = tid >> 6;
  const int jg = wid >> 2;        // 0..1 : which 64 of the 128 z-dims
  const int bg = wid & 3;         // 0..3 : which 64 of the 256 points
  const int l15 = ln & 15, lg = ln >> 4;
  const size_t p0 = (size_t)blockIdx.x * 256;

  // stage x tile: fp32 -> bf16, XOR-swizzled writes (coalesced float4 reads)
  for (int t = tid; t < 256 * 128 / 4; t += 512) {
    const float4 v = *reinterpret_cast<const float4*>(&x[p0 * D + (size_t)t * 4]);
    const int flat = t * 4, row = flat >> 7, col = flat & 127;
    ushort4 h;
    h.x = f2bf(v.x); h.y = f2bf(v.y); h.z = f2bf(v.z); h.w = f2bf(v.w);
    *reinterpret_cast<ushort4*>(&xbuf[row * 128 + (col ^ ((row & 7) << 3))]) = h;
  }
  for (int t = tid; t < 256 * 16; t += 512)
    pT[(t >> 4) * 17 + (t & 15)] = f2bf(probs[p0 * NK + t]);
  for (int t = tid; t < NK * D; t += 512) Lm[t] = LmuG[t];
  if (tid < NK) ld_s[tid] = ldG[tid];

  stage_tile(WG, &Albuf[0][0], tid);   // state 0 Linv tile
  __syncthreads();

  float vt = 117.62413225f;            // 0.5*D*ln(2*pi); sum_k p_k == 1

  const int sw = (l15 & 7) << 3;       // XOR swizzle term

  for (int k = 0; k < NK; ++k) {
    if (k < NK - 1) stage_tile(WG + (size_t)(k + 1) * D * D, &Albuf[(k + 1) & 1][0], tid);

    const unsigned short* Ab = &Albuf[k & 1][0];
    f32x4 acc[4][4];
#pragma unroll
    for (int m = 0; m < 4; ++m)
#pragma unroll
      for (int n = 0; n < 4; ++n) acc[m][n] = (f32x4){0.f, 0.f, 0.f, 0.f};

#pragma unroll
    for (int ks = 0; ks < 4; ++ks) {
      const int kbs = (ks * 32 + lg * 8) ^ sw;
      bf16x8 a[4], b[4];
#pragma unroll
      for (int m = 0; m < 4; ++m) {
        const int arow = jg * 64 + m * 16 + l15;
        a[m] = *reinterpret_cast<const bf16x8*>(&Ab[arow * 128 + kbs]);
      }
#pragma unroll
      for (int n = 0; n < 4; ++n) {
        const int brow = bg * 64 + n * 16 + l15;
        b[n] = *reinterpret_cast<const bf16x8*>(&xbuf[brow * 128 + kbs]);
      }
#pragma unroll
      for (int m = 0; m < 4; ++m)
#pragma unroll
        for (int n = 0; n < 4; ++n)
          acc[m][n] = __builtin_amdgcn_mfma_f32_16x16x32_bf16(a[m], b[n], acc[m][n], 0, 0, 0);
    }

    // epilogue: maha partials, lane-local j-reduction then xor across lane groups
    float lmv[4][4];
    const int jb = jg * 64 + lg * 4;
#pragma unroll
    for (int m = 0; m < 4; ++m)
#pragma unroll
      for (int r = 0; r < 4; ++r) lmv[m][r] = Lm[k * D + jb + m * 16 + r];
#pragma unroll
    for (int n = 0; n < 4; ++n) {
      float s = 0.f;
#pragma unroll
      for (int m = 0; m < 4; ++m)
#pragma unroll
        for (int r = 0; r < 4; ++r) {
          const float y = acc[m][n][r] - lmv[m][r];
          s = fmaf(y, y, s);
        }
      s += __shfl_xor(s, 16);
      s += __shfl_xor(s, 32);
      if (ln < 16) mah2[k & 1][jg][bg * 64 + n * 16 + ln] = s;
    }
    __syncthreads();   // also drains vmcnt -> next A tile resident

    if (tid < 256) {
      const float maha = mah2[k & 1][0][tid] + mah2[k & 1][1][tid];
      vt = fmaf(bf2f(pT[tid * 17 + k]), fmaf(0.5f, maha, ld_s[k]), vt);
    }
  }

  if (tid < 256) red[tid] = vt;
  __syncthreads();
  for (int s = 128; s > 0; s >>= 1) {
    if (tid < s) red[tid] += red[tid + s];
    __syncthreads();
  }
  if (tid == 0) atomicAdd(out, red[0] * (1.0f / 64.0f));
}

extern "C" void kernel_launch(void* const* d_in, const int* in_sizes, int n_in,
                              void* d_out, int out_size, void* d_ws, size_t ws_size,
                              hipStream_t stream) {
  const float* x     = (const float*)d_in[0];
  const float* mu    = (const float*)d_in[1];
  const float* sigma = (const float*)d_in[2];
  const float* probs = (const float*)d_in[3];
  float* out = (float*)d_out;

  unsigned short* WG = (unsigned short*)d_ws;          // 16*128*128 bf16 = 512 KB
  float* LmuG = (float*)(WG + (size_t)NK * D * D);     // 8 KB
  float* ldG  = LmuG + NK * D;                         // 64 B

  setup_kernel<<<NK, 256, 0, stream>>>(sigma, mu, WG, LmuG, ldG, out);
  main_kernel<<<BT / 256, 512, 0, stream>>>(x, probs, WG, LmuG, ldG, out);
}

// Round 4
// 313.899 us; speedup vs baseline: 1.7427x; 1.7427x over previous
//
#include <hip/hip_runtime.h>
#include <hip/hip_bf16.h>

#define D 128
#define NK 16
#define BT (64*2048)

typedef short bf16x8 __attribute__((ext_vector_type(8)));
typedef float f32x4 __attribute__((ext_vector_type(4)));

__device__ __forceinline__ unsigned short f2bf(float f) {
  unsigned u = __builtin_bit_cast(unsigned, f);
  unsigned r = (u + 0x7FFFu + ((u >> 16) & 1u)) >> 16;   // round-to-nearest-even
  return (unsigned short)r;
}
__device__ __forceinline__ float bf2f(unsigned short h) {
  unsigned u = ((unsigned)h) << 16;
  return __builtin_bit_cast(float, u);
}

// ---------------- Setup: Cholesky -> logdet, Linv (bf16 swizzled image), Lmu = Linv*mu ----------
// 256 threads/state. R3 lesson: LDS RMW loops on one array serialize at ~130cy/iter because the
// compiler can't disprove aliasing. Fix: broadcast the pivot column through a SEPARATE cb[] array
// (provably no-alias vs A row RMW), row updates as float4 chunks from one base pointer.
__global__ __launch_bounds__(256) void setup_kernel(const float* __restrict__ sigma,
                                                    const float* __restrict__ mu,
                                                    unsigned short* __restrict__ WG,
                                                    float* __restrict__ LmuG,
                                                    float* __restrict__ ldG,
                                                    float* __restrict__ out) {
  __shared__ float A[D][132];          // sigma -> L (lower); cols 128..131 = scratch padding
  __shared__ float V[D][129];          // Linv (lower), upper zeroed
  __shared__ float T[3][32][33];       // per-pair matmul temps
  __shared__ float cb[132];            // scaled pivot column (L[r][j]), r-indexed
  __shared__ float dgl[D], invd[D], logv[D];
  const int tid = threadIdx.x;
  const int k = blockIdx.x;
  const float* S = sigma + (size_t)k * D * D;

  if (k == 0 && tid == 0) out[0] = 0.f;

  for (int t = tid; t < D * D; t += 256) {
    A[t >> 7][t & 127] = S[t];
    V[t >> 7][t & 127] = 0.f;
  }
  __syncthreads();

  // ---- Cholesky: right-looking rank-1, cb-mediated (alias-free update) ----
  for (int j = 0; j < D; ++j) {
    const float d = A[j][j];               // updated through iter j-1; not overwritten below
    {
      const int r = j + tid;
      if (r < D) {
        const float sq = sqrtf(d);
        if (tid == 0) {
          dgl[j] = sq;                     // final L diag kept out of A (avoids read/write race)
        } else {
          const float lv = A[r][j] * (1.0f / sq);
          A[r][j] = lv;                    // final L[r][j]
          cb[r] = lv;
        }
      }
    }
    __syncthreads();                       // cb / column j final
    {
      const int r = j + 1 + (tid >> 1);
      if (r < D) {
        const float lr = cb[r];
        float* rowp = &A[r][0];
        const int c0 = (j + 1) & ~3;       // 16B-aligned chunk start
        const int nch = ((r - c0) + 4) >> 2;  // chunks covering [c0..r]; tail past r is padding junk
        for (int idx = (tid & 1); idx < nch; idx += 2) {
          const int c4 = c0 + idx * 4;
          float4 av = *reinterpret_cast<float4*>(&rowp[c4]);
          const float4 cv = *reinterpret_cast<const float4*>(&cb[c4]);
          av.x = (c4 + 0 > j) ? fmaf(-lr, cv.x, av.x) : av.x;
          av.y = (c4 + 1 > j) ? fmaf(-lr, cv.y, av.y) : av.y;
          av.z = (c4 + 2 > j) ? fmaf(-lr, cv.z, av.z) : av.z;
          av.w = (c4 + 3 > j) ? fmaf(-lr, cv.w, av.w) : av.w;
          *reinterpret_cast<float4*>(&rowp[c4]) = av;
        }
      }
    }
    __syncthreads();                       // update done; cb reusable next iter
  }

  if (tid < D) {
    const float dg = dgl[tid];
    invd[tid] = 1.f / dg;
    logv[tid] = logf(dg);
  }

  // ---- blocked triangular inverse: 4 diag 32x32 blocks, col per thread (chain <= 32) ----
  __syncthreads();
  if (tid < D) {
    const int c = tid, bend = ((c >> 5) + 1) << 5;
    V[c][c] = invd[c];
    for (int r = c + 1; r < bend; ++r) {
      float s = 0.f;
      for (int p = c; p < r; ++p) s += A[r][p] * V[p][c];
      V[r][c] = -s * invd[r];
    }
  }

  // ---- off-diagonal blocks, 3 dependency levels, register-blocked matmuls ----
  for (int d = 1; d <= 3; ++d) {
    __syncthreads();
    const int npair = 4 - d;
    for (int q = tid; q < npair * 256; q += 256) {       // phase A: M = L*V into T
      const int pair = q >> 8;
      const int r = (q >> 3) & 31;
      const int c4 = (q & 7) << 2;
      const int i0 = (pair + d) << 5, j0 = pair << 5;
      float m0 = 0.f, m1 = 0.f, m2 = 0.f, m3 = 0.f;
      for (int p = 0; p < d * 32; ++p) {
        const float a = A[i0 + r][j0 + p];
        const float* vp = &V[j0 + p][j0 + c4];
        m0 = fmaf(a, vp[0], m0); m1 = fmaf(a, vp[1], m1);
        m2 = fmaf(a, vp[2], m2); m3 = fmaf(a, vp[3], m3);
      }
      T[pair][r][c4] = m0; T[pair][r][c4 + 1] = m1;
      T[pair][r][c4 + 2] = m2; T[pair][r][c4 + 3] = m3;
    }
    __syncthreads();
    for (int q = tid; q < npair * 256; q += 256) {       // phase B: V_ij = -V_ii * M
      const int pair = q >> 8;
      const int r = (q >> 3) & 31;
      const int c4 = (q & 7) << 2;
      const int i0 = (pair + d) << 5, j0 = pair << 5;
      float m0 = 0.f, m1 = 0.f, m2 = 0.f, m3 = 0.f;
      for (int p = 0; p <= r; ++p) {                     // V_ii lower-triangular, diag = invd
        const float a = V[i0 + r][i0 + p];
        const float* tp = &T[pair][p][c4];
        m0 = fmaf(a, tp[0], m0); m1 = fmaf(a, tp[1], m1);
        m2 = fmaf(a, tp[2], m2); m3 = fmaf(a, tp[3], m3);
      }
      V[i0 + r][j0 + c4] = -m0; V[i0 + r][j0 + c4 + 1] = -m1;
      V[i0 + r][j0 + c4 + 2] = -m2; V[i0 + r][j0 + c4 + 3] = -m3;
    }
  }
  __syncthreads();

  // Lmu[k][j] = sum_i Linv[j][i]*mu[k][i]  (V upper = 0 -> uniform loop)
  if (tid < D) {
    const float* muk = mu + k * D;
    float s = 0.f;
    for (int i = 0; i < D; ++i) s = fmaf(V[tid][i], muk[i], s);
    LmuG[k * D + tid] = s;
  }
  if (tid == 0) {
    float s = 0.f;
    for (int i = 0; i < D; ++i) s += logv[i];
    ldG[k] = s;
  }
  // bf16 image of Linv, pre-swizzled so linear global_load_lds lands XOR-swizzled in LDS
  for (int t = tid; t < D * D; t += 256) {
    const int j = t >> 7, i = t & 127;
    WG[(size_t)k * D * D + j * D + (i ^ ((j & 7) << 3))] = f2bf(V[j][i]);
  }
}

__device__ __forceinline__ void stage_tile(const unsigned short* gsrc, unsigned short* lds, int tid) {
#pragma unroll
  for (int c = 0; c < 4; ++c) {
    const int off = c * 4096 + tid * 8;  // u16 units; 16B per lane
    __builtin_amdgcn_global_load_lds(
        (const __attribute__((address_space(1))) unsigned int*)(gsrc + off),
        (__attribute__((address_space(3))) unsigned int*)(lds + off), 16, 0, 0);
  }
}

// ---------------- Main: Z^T = Linv * x^T per state (MFMA), maha = ||Z - Lmu||^2 ----------------
// 512 threads = 8 waves (2 j-groups x 4 bt-groups), 256 points/block, grid = 512
__global__ __launch_bounds__(512, 2) void main_kernel(const float* __restrict__ x,
                                                      const float* __restrict__ probs,
                                                      const unsigned short* __restrict__ WG,
                                                      const float* __restrict__ LmuG,
                                                      const float* __restrict__ ldG,
                                                      float* __restrict__ out) {
  __shared__ unsigned short xbuf[256 * 128];        // 64 KB, XOR-swizzled bf16 x
  __shared__ unsigned short Albuf[2][128 * 128];    // 64 KB, double-buffered swizzled Linv
  __shared__ float Lm[NK * D];                      // 8 KB
  __shared__ unsigned short pT[256 * 17];           // 8.5 KB, bf16 probs (padded stride 17)
  __shared__ float mah2[2][2][256];                 // 8 KB
  __shared__ float ld_s[NK];
  __shared__ float red[256];

  const int tid = threadIdx.x;
  const int ln = tid & 63;
  const int wid = tid >> 6;
  const int jg = wid >> 2;        // 0..1 : which 64 of the 128 z-dims
  const int bg = wid & 3;         // 0..3 : which 64 of the 256 points
  const int l15 = ln & 15, lg = ln >> 4;
  const size_t p0 = (size_t)blockIdx.x * 256;

  // stage x tile: fp32 -> bf16, XOR-swizzled writes (coalesced float4 reads)
  for (int t = tid; t < 256 * 128 / 4; t += 512) {
    const float4 v = *reinterpret_cast<const float4*>(&x[p0 * D + (size_t)t * 4]);
    const int flat = t * 4, row = flat >> 7, col = flat & 127;
    ushort4 h;
    h.x = f2bf(v.x); h.y = f2bf(v.y); h.z = f2bf(v.z); h.w = f2bf(v.w);
    *reinterpret_cast<ushort4*>(&xbuf[row * 128 + (col ^ ((row & 7) << 3))]) = h;
  }
  for (int t = tid; t < 256 * 16; t += 512)
    pT[(t >> 4) * 17 + (t & 15)] = f2bf(probs[p0 * NK + t]);
  for (int t = tid; t < NK * D; t += 512) Lm[t] = LmuG[t];
  if (tid < NK) ld_s[tid] = ldG[tid];

  stage_tile(WG, &Albuf[0][0], tid);   // state 0 Linv tile
  __syncthreads();

  float vt = 117.62413225f;            // 0.5*D*ln(2*pi); sum_k p_k == 1

  const int sw = (l15 & 7) << 3;       // XOR swizzle term

  for (int k = 0; k < NK; ++k) {
    if (k < NK - 1) stage_tile(WG + (size_t)(k + 1) * D * D, &Albuf[(k + 1) & 1][0], tid);

    const unsigned short* Ab = &Albuf[k & 1][0];
    f32x4 acc[4][4];
#pragma unroll
    for (int m = 0; m < 4; ++m)
#pragma unroll
      for (int n = 0; n < 4; ++n) acc[m][n] = (f32x4){0.f, 0.f, 0.f, 0.f};

#pragma unroll
    for (int ks = 0; ks < 4; ++ks) {
      const int kbs = (ks * 32 + lg * 8) ^ sw;
      bf16x8 a[4], b[4];
#pragma unroll
      for (int m = 0; m < 4; ++m) {
        const int arow = jg * 64 + m * 16 + l15;
        a[m] = *reinterpret_cast<const bf16x8*>(&Ab[arow * 128 + kbs]);
      }
#pragma unroll
      for (int n = 0; n < 4; ++n) {
        const int brow = bg * 64 + n * 16 + l15;
        b[n] = *reinterpret_cast<const bf16x8*>(&xbuf[brow * 128 + kbs]);
      }
#pragma unroll
      for (int m = 0; m < 4; ++m)
#pragma unroll
        for (int n = 0; n < 4; ++n)
          acc[m][n] = __builtin_amdgcn_mfma_f32_16x16x32_bf16(a[m], b[n], acc[m][n], 0, 0, 0);
    }

    // epilogue: maha partials, lane-local j-reduction then xor across lane groups
    float lmv[4][4];
    const int jb = jg * 64 + lg * 4;
#pragma unroll
    for (int m = 0; m < 4; ++m)
#pragma unroll
      for (int r = 0; r < 4; ++r) lmv[m][r] = Lm[k * D + jb + m * 16 + r];
#pragma unroll
    for (int n = 0; n < 4; ++n) {
      float s = 0.f;
#pragma unroll
      for (int m = 0; m < 4; ++m)
#pragma unroll
        for (int r = 0; r < 4; ++r) {
          const float y = acc[m][n][r] - lmv[m][r];
          s = fmaf(y, y, s);
        }
      s += __shfl_xor(s, 16);
      s += __shfl_xor(s, 32);
      if (ln < 16) mah2[k & 1][jg][bg * 64 + n * 16 + ln] = s;
    }
    __syncthreads();   // also drains vmcnt -> next A tile resident

    if (tid < 256) {
      const float maha = mah2[k & 1][0][tid] + mah2[k & 1][1][tid];
      vt = fmaf(bf2f(pT[tid * 17 + k]), fmaf(0.5f, maha, ld_s[k]), vt);
    }
  }

  if (tid < 256) red[tid] = vt;
  __syncthreads();
  for (int s = 128; s > 0; s >>= 1) {
    if (tid < s) red[tid] += red[tid + s];
    __syncthreads();
  }
  if (tid == 0) atomicAdd(out, red[0] * (1.0f / 64.0f));
}

extern "C" void kernel_launch(void* const* d_in, const int* in_sizes, int n_in,
                              void* d_out, int out_size, void* d_ws, size_t ws_size,
                              hipStream_t stream) {
  const float* x     = (const float*)d_in[0];
  const float* mu    = (const float*)d_in[1];
  const float* sigma = (const float*)d_in[2];
  const float* probs = (const float*)d_in[3];
  float* out = (float*)d_out;

  unsigned short* WG = (unsigned short*)d_ws;          // 16*128*128 bf16 = 512 KB
  float* LmuG = (float*)(WG + (size_t)NK * D * D);     // 8 KB
  float* ldG  = LmuG + NK * D;                         // 64 B

  setup_kernel<<<NK, 256, 0, stream>>>(sigma, mu, WG, LmuG, ldG, out);
  main_kernel<<<BT / 256, 512, 0, stream>>>(x, probs, WG, LmuG, ldG, out);
}

// Round 5
// 298.653 us; speedup vs baseline: 1.8317x; 1.0510x over previous
//
#include <hip/hip_runtime.h>
#include <hip/hip_bf16.h>

#define D 128
#define NK 16
#define BT (64*2048)

typedef short bf16x8 __attribute__((ext_vector_type(8)));
typedef float f32x4 __attribute__((ext_vector_type(4)));

__device__ __forceinline__ unsigned short f2bf(float f) {
  unsigned u = __builtin_bit_cast(unsigned, f);
  unsigned r = (u + 0x7FFFu + ((u >> 16) & 1u)) >> 16;   // round-to-nearest-even
  return (unsigned short)r;
}
__device__ __forceinline__ float bf2f(unsigned short h) {
  unsigned u = ((unsigned)h) << 16;
  return __builtin_bit_cast(float, u);
}

// ---------------- Setup: Cholesky -> logdet, Linv (bf16 swizzled image), Lmu = Linv*mu ----------
// R4 lesson: the trailing-update float4 LDS RMW chain serializes at ~260cy/chunk (load waits on
// previous store to same array). R5: batch-registerize — load 8 A-chunks + 8 cb-chunks with no
// intervening stores (one lgkmcnt drain), FMA in regs, store all.
__global__ __launch_bounds__(256) void setup_kernel(const float* __restrict__ sigma,
                                                    const float* __restrict__ mu,
                                                    unsigned short* __restrict__ WG,
                                                    float* __restrict__ LmuG,
                                                    float* __restrict__ ldG,
                                                    float* __restrict__ out) {
  __shared__ float A[D][132];          // sigma -> L (lower); cols 128..131 = scratch padding
  __shared__ float V[D][129];          // Linv (lower), upper zeroed
  __shared__ float T[3][32][33];       // per-pair matmul temps
  __shared__ float cb[132];            // scaled pivot column (L[r][j]), r-indexed
  __shared__ float dgl[D], invd[D], logv[D];
  const int tid = threadIdx.x;
  const int k = blockIdx.x;
  const float* S = sigma + (size_t)k * D * D;

  if (k == 0 && tid == 0) out[0] = 0.f;

  for (int t = tid; t < D * D; t += 256) {
    A[t >> 7][t & 127] = S[t];
    V[t >> 7][t & 127] = 0.f;
  }
  __syncthreads();

  // ---- Cholesky: right-looking rank-1, cb-mediated, register-batched update ----
  for (int j = 0; j < D; ++j) {
    const float d = A[j][j];               // fresh: barrier at end of previous iter
    {
      const int r = j + tid;
      if (r < D) {
        const float sq = sqrtf(d);
        if (tid == 0) {
          dgl[j] = sq;                     // final L diag kept out of A
        } else {
          const float lv = A[r][j] * (1.0f / sq);
          A[r][j] = lv;                    // final L[r][j]
          cb[r] = lv;
        }
      }
    }
    __syncthreads();                       // cb / column j final
    {
      const int r = j + 1 + (tid >> 1);
      if (r < D) {
        const float lr = -cb[r];
        float* rowp = &A[r][0];
        const float4* cbp = reinterpret_cast<const float4*>(cb);
        const int c0 = (j + 1) & ~3;       // 16B-aligned chunk start
        const int q0 = c0 >> 2;
        const int nch = ((r - c0) + 4) >> 2;  // chunks covering [c0..r] (tail junk stays in pad)
        const int myoff = tid & 1;            // 2 threads/row, interleaved chunks
#pragma unroll
        for (int half = 0; half < 2; ++half) {
          float4 rv[8], cv[8];
#pragma unroll
          for (int s = 0; s < 8; ++s) {        // all loads first: no load-after-store chain
            const int idx = myoff + 2 * (half * 8 + s);
            if (idx < nch) {
              rv[s] = *reinterpret_cast<const float4*>(&rowp[c0 + idx * 4]);
              cv[s] = cbp[q0 + idx];
            }
          }
#pragma unroll
          for (int s = 0; s < 8; ++s) {
            const int idx = myoff + 2 * (half * 8 + s);
            if (idx < nch) {
              const int c4 = c0 + idx * 4;
              float4 av = rv[s];
              const float4 cvv = cv[s];
              av.x = (c4 + 0 > j) ? fmaf(lr, cvv.x, av.x) : av.x;
              av.y = (c4 + 1 > j) ? fmaf(lr, cvv.y, av.y) : av.y;
              av.z = (c4 + 2 > j) ? fmaf(lr, cvv.z, av.z) : av.z;
              av.w = (c4 + 3 > j) ? fmaf(lr, cvv.w, av.w) : av.w;
              *reinterpret_cast<float4*>(&rowp[c4]) = av;
            }
          }
        }
      }
    }
    __syncthreads();                       // update done; cb reusable next iter
  }

  if (tid < D) {
    const float dg = dgl[tid];
    invd[tid] = 1.f / dg;
    logv[tid] = logf(dg);
  }

  // ---- blocked triangular inverse: 4 diag 32x32 blocks, col per thread (chain <= 32) ----
  __syncthreads();
  if (tid < D) {
    const int c = tid, bend = ((c >> 5) + 1) << 5;
    V[c][c] = invd[c];
    for (int r = c + 1; r < bend; ++r) {
      float s = 0.f;
      for (int p = c; p < r; ++p) s += A[r][p] * V[p][c];
      V[r][c] = -s * invd[r];
    }
  }

  // ---- off-diagonal blocks, 3 dependency levels, register-blocked matmuls ----
  for (int d = 1; d <= 3; ++d) {
    __syncthreads();
    const int npair = 4 - d;
    for (int q = tid; q < npair * 256; q += 256) {       // phase A: M = L*V into T
      const int pair = q >> 8;
      const int r = (q >> 3) & 31;
      const int c4 = (q & 7) << 2;
      const int i0 = (pair + d) << 5, j0 = pair << 5;
      float m0 = 0.f, m1 = 0.f, m2 = 0.f, m3 = 0.f;
      for (int p = 0; p < d * 32; ++p) {
        const float a = A[i0 + r][j0 + p];
        const float* vp = &V[j0 + p][j0 + c4];
        m0 = fmaf(a, vp[0], m0); m1 = fmaf(a, vp[1], m1);
        m2 = fmaf(a, vp[2], m2); m3 = fmaf(a, vp[3], m3);
      }
      T[pair][r][c4] = m0; T[pair][r][c4 + 1] = m1;
      T[pair][r][c4 + 2] = m2; T[pair][r][c4 + 3] = m3;
    }
    __syncthreads();
    for (int q = tid; q < npair * 256; q += 256) {       // phase B: V_ij = -V_ii * M
      const int pair = q >> 8;
      const int r = (q >> 3) & 31;
      const int c4 = (q & 7) << 2;
      const int i0 = (pair + d) << 5, j0 = pair << 5;
      float m0 = 0.f, m1 = 0.f, m2 = 0.f, m3 = 0.f;
      for (int p = 0; p <= r; ++p) {                     // V_ii lower-triangular
        const float a = V[i0 + r][i0 + p];
        const float* tp = &T[pair][p][c4];
        m0 = fmaf(a, tp[0], m0); m1 = fmaf(a, tp[1], m1);
        m2 = fmaf(a, tp[2], m2); m3 = fmaf(a, tp[3], m3);
      }
      V[i0 + r][j0 + c4] = -m0; V[i0 + r][j0 + c4 + 1] = -m1;
      V[i0 + r][j0 + c4 + 2] = -m2; V[i0 + r][j0 + c4 + 3] = -m3;
    }
  }
  __syncthreads();

  // Lmu[k][j] = sum_i Linv[j][i]*mu[k][i]  (V upper = 0 -> uniform loop)
  if (tid < D) {
    const float* muk = mu + k * D;
    float s = 0.f;
    for (int i = 0; i < D; ++i) s = fmaf(V[tid][i], muk[i], s);
    LmuG[k * D + tid] = s;
  }
  if (tid < 64) {                                        // wave-parallel logdet reduce
    float s = logv[tid] + logv[tid + 64];
    s += __shfl_xor(s, 32); s += __shfl_xor(s, 16);
    s += __shfl_xor(s, 8);  s += __shfl_xor(s, 4);
    s += __shfl_xor(s, 2);  s += __shfl_xor(s, 1);
    if (tid == 0) ldG[k] = s;
  }
  // bf16 image of Linv, pre-swizzled so linear global_load_lds lands XOR-swizzled in LDS
  for (int t = tid; t < D * D; t += 256) {
    const int j = t >> 7, i = t & 127;
    WG[(size_t)k * D * D + j * D + (i ^ ((j & 7) << 3))] = f2bf(V[j][i]);
  }
}

__device__ __forceinline__ void stage_tile(const unsigned short* gsrc, unsigned short* lds, int tid) {
#pragma unroll
  for (int c = 0; c < 4; ++c) {
    const int off = c * 4096 + tid * 8;  // u16 units; 16B per lane
    __builtin_amdgcn_global_load_lds(
        (const __attribute__((address_space(1))) unsigned int*)(gsrc + off),
        (__attribute__((address_space(3))) unsigned int*)(lds + off), 16, 0, 0);
  }
}

// ---------------- Main: Z^T = Linv * x^T per state (MFMA), maha = ||Z - Lmu||^2 ----------------
// 512 threads = 8 waves (2 j-groups x 4 bt-groups), 256 points/block, grid = 512
__global__ __launch_bounds__(512, 2) void main_kernel(const float* __restrict__ x,
                                                      const float* __restrict__ probs,
                                                      const unsigned short* __restrict__ WG,
                                                      const float* __restrict__ LmuG,
                                                      const float* __restrict__ ldG,
                                                      float* __restrict__ out) {
  __shared__ unsigned short xbuf[256 * 128];        // 64 KB, XOR-swizzled bf16 x
  __shared__ unsigned short Albuf[2][128 * 128];    // 64 KB, double-buffered swizzled Linv
  __shared__ float Lm[NK * D];                      // 8 KB
  __shared__ unsigned short pT[256 * 17];           // 8.5 KB, bf16 probs (padded stride 17)
  __shared__ float mah2[2][2][256];                 // 8 KB
  __shared__ float ld_s[NK];
  __shared__ float red[256];

  const int tid = threadIdx.x;
  const int ln = tid & 63;
  const int wid = tid >> 6;
  const int jg = wid >> 2;        // 0..1 : which 64 of the 128 z-dims
  const int bg = wid & 3;         // 0..3 : which 64 of the 256 points
  const int l15 = ln & 15, lg = ln >> 4;
  const size_t p0 = (size_t)blockIdx.x * 256;

  // stage x tile: fp32 -> bf16, XOR-swizzled writes (coalesced float4 reads)
  for (int t = tid; t < 256 * 128 / 4; t += 512) {
    const float4 v = *reinterpret_cast<const float4*>(&x[p0 * D + (size_t)t * 4]);
    const int flat = t * 4, row = flat >> 7, col = flat & 127;
    ushort4 h;
    h.x = f2bf(v.x); h.y = f2bf(v.y); h.z = f2bf(v.z); h.w = f2bf(v.w);
    *reinterpret_cast<ushort4*>(&xbuf[row * 128 + (col ^ ((row & 7) << 3))]) = h;
  }
  for (int t = tid; t < 256 * 16; t += 512)
    pT[(t >> 4) * 17 + (t & 15)] = f2bf(probs[p0 * NK + t]);
  for (int t = tid; t < NK * D; t += 512) Lm[t] = LmuG[t];
  if (tid < NK) ld_s[tid] = ldG[tid];

  stage_tile(WG, &Albuf[0][0], tid);   // state 0 Linv tile
  __syncthreads();

  float vt = 117.62413225f;            // 0.5*D*ln(2*pi); sum_k p_k == 1

  const int sw = (l15 & 7) << 3;       // XOR swizzle term

  for (int k = 0; k < NK; ++k) {
    if (k < NK - 1) stage_tile(WG + (size_t)(k + 1) * D * D, &Albuf[(k + 1) & 1][0], tid);

    const unsigned short* Ab = &Albuf[k & 1][0];
    f32x4 acc[4][4];
#pragma unroll
    for (int m = 0; m < 4; ++m)
#pragma unroll
      for (int n = 0; n < 4; ++n) acc[m][n] = (f32x4){0.f, 0.f, 0.f, 0.f};

#pragma unroll
    for (int ks = 0; ks < 4; ++ks) {
      const int kbs = (ks * 32 + lg * 8) ^ sw;
      bf16x8 a[4], b[4];
#pragma unroll
      for (int m = 0; m < 4; ++m) {
        const int arow = jg * 64 + m * 16 + l15;
        a[m] = *reinterpret_cast<const bf16x8*>(&Ab[arow * 128 + kbs]);
      }
#pragma unroll
      for (int n = 0; n < 4; ++n) {
        const int brow = bg * 64 + n * 16 + l15;
        b[n] = *reinterpret_cast<const bf16x8*>(&xbuf[brow * 128 + kbs]);
      }
#pragma unroll
      for (int m = 0; m < 4; ++m)
#pragma unroll
        for (int n = 0; n < 4; ++n)
          acc[m][n] = __builtin_amdgcn_mfma_f32_16x16x32_bf16(a[m], b[n], acc[m][n], 0, 0, 0);
    }

    // epilogue: maha partials, lane-local j-reduction then xor across lane groups
    float lmv[4][4];
    const int jb = jg * 64 + lg * 4;
#pragma unroll
    for (int m = 0; m < 4; ++m)
#pragma unroll
      for (int r = 0; r < 4; ++r) lmv[m][r] = Lm[k * D + jb + m * 16 + r];
#pragma unroll
    for (int n = 0; n < 4; ++n) {
      float s = 0.f;
#pragma unroll
      for (int m = 0; m < 4; ++m)
#pragma unroll
        for (int r = 0; r < 4; ++r) {
          const float y = acc[m][n][r] - lmv[m][r];
          s = fmaf(y, y, s);
        }
      s += __shfl_xor(s, 16);
      s += __shfl_xor(s, 32);
      if (ln < 16) mah2[k & 1][jg][bg * 64 + n * 16 + ln] = s;
    }
    __syncthreads();   // also drains vmcnt -> next A tile resident

    if (tid < 256) {
      const float maha = mah2[k & 1][0][tid] + mah2[k & 1][1][tid];
      vt = fmaf(bf2f(pT[tid * 17 + k]), fmaf(0.5f, maha, ld_s[k]), vt);
    }
  }

  if (tid < 256) red[tid] = vt;
  __syncthreads();
  for (int s = 128; s > 0; s >>= 1) {
    if (tid < s) red[tid] += red[tid + s];
    __syncthreads();
  }
  if (tid == 0) atomicAdd(out, red[0] * (1.0f / 64.0f));
}

extern "C" void kernel_launch(void* const* d_in, const int* in_sizes, int n_in,
                              void* d_out, int out_size, void* d_ws, size_t ws_size,
                              hipStream_t stream) {
  const float* x     = (const float*)d_in[0];
  const float* mu    = (const float*)d_in[1];
  const float* sigma = (const float*)d_in[2];
  const float* probs = (const float*)d_in[3];
  float* out = (float*)d_out;

  unsigned short* WG = (unsigned short*)d_ws;          // 16*128*128 bf16 = 512 KB
  float* LmuG = (float*)(WG + (size_t)NK * D * D);     // 8 KB
  float* ldG  = LmuG + NK * D;                         // 64 B

  setup_kernel<<<NK, 256, 0, stream>>>(sigma, mu, WG, LmuG, ldG, out);
  main_kernel<<<BT / 256, 512, 0, stream>>>(x, probs, WG, LmuG, ldG, out);
}